// Round 1
// baseline (384.248 us; speedup 1.0000x reference)
//
#include <hip/hip_runtime.h>
#include <hip/hip_bf16.h>
#include <stdint.h>

// Problem constants (BS, SL, D, H) = (8, 1024, 1024, 16), DK = 64.
#define BSZ 8
#define SLEN 1024
#define DMODEL 1024
#define NH 16
#define HD 64
#define MROWS (BSZ * SLEN)  // 8192

typedef __bf16 bf16_t;
typedef __bf16 bf16x8 __attribute__((ext_vector_type(8)));
typedef __bf16 bf16x4 __attribute__((ext_vector_type(4)));
typedef float f32x4 __attribute__((ext_vector_type(4)));

__device__ __forceinline__ void gload_lds16(const void* g, void* l) {
    __builtin_amdgcn_global_load_lds(
        (const __attribute__((address_space(1))) unsigned int*)g,
        (__attribute__((address_space(3))) unsigned int*)l,
        16, 0, 0);
}

// ---------------- fp32 -> bf16 convert (vectorized) ----------------
__global__ __launch_bounds__(256) void cvt_f32_to_bf16(
    const float* __restrict__ src, bf16_t* __restrict__ dst, int n4) {
    int i = blockIdx.x * blockDim.x + threadIdx.x;
    if (i >= n4) return;
    const float4 v = reinterpret_cast<const float4*>(src)[i];
    bf16x4 o;
    o[0] = (bf16_t)v.x; o[1] = (bf16_t)v.y; o[2] = (bf16_t)v.z; o[3] = (bf16_t)v.w;
    reinterpret_cast<bf16x4*>(dst)[i] = o;
}

// ---------------- 128x128 bf16 GEMM, C = A @ B^T (m97 structure) ----------------
// A: M x K row-major bf16.  B: N x K row-major bf16 (per-batch if bstride != 0).
// FINAL == 0: C bf16, epilogue += bias[col].
// FINAL == 1: C fp32; out = mask[b,s] ? acc*0.125 + bias[col] : trow[b*DMODEL+col].
template <int FINAL>
__global__ __launch_bounds__(256) void gemm_bt(
    const bf16_t* __restrict__ A, const bf16_t* __restrict__ B,
    void* __restrict__ C, const float* __restrict__ bias,
    const float* __restrict__ trow, const int* __restrict__ mask,
    int M, int N, int K, int bstride) {
    __shared__ bf16_t As[128 * 32];
    __shared__ bf16_t Bs[128 * 32];
    const int tid = threadIdx.x;
    const int m0 = blockIdx.y * 128;
    const int n0 = blockIdx.x * 128;
    const bf16_t* Bp = B + (size_t)(m0 >> 10) * (size_t)bstride;

    // staging coords: thread t covers 16B at LDS offset t*16 (linear, gload_lds-safe)
    const int srow = tid >> 2;         // 0..63
    const int scol = (tid & 3) * 8;    // 0,8,16,24
    const bf16_t* Ag = A + (size_t)(m0 + srow) * K + scol;
    const bf16_t* Bg = Bp + (size_t)(n0 + srow) * K + scol;
    bf16_t* Asl = As + srow * 32 + scol;
    bf16_t* Bsl = Bs + srow * 32 + scol;

    const int lane = tid & 63;
    const int wave = tid >> 6;
    const int wr = (wave >> 1) * 64;   // wave row origin in tile
    const int wc = (wave & 1) * 64;    // wave col origin in tile
    const int lr = lane & 15;
    const int lk = (lane >> 4) * 8;

    f32x4 acc[4][4] = {};

    for (int kt = 0; kt < K; kt += 32) {
        gload_lds16(Ag + kt, Asl);
        gload_lds16(Ag + kt + (size_t)64 * K, Asl + 64 * 32);
        gload_lds16(Bg + kt, Bsl);
        gload_lds16(Bg + kt + (size_t)64 * K, Bsl + 64 * 32);
        __syncthreads();   // compiler drains vmcnt before barrier
        bf16x8 aw[4], bw[4];
#pragma unroll
        for (int i = 0; i < 4; ++i)
            aw[i] = *reinterpret_cast<const bf16x8*>(&As[(wr + i * 16 + lr) * 32 + lk]);
#pragma unroll
        for (int i = 0; i < 4; ++i)
            bw[i] = *reinterpret_cast<const bf16x8*>(&Bs[(wc + i * 16 + lr) * 32 + lk]);
#pragma unroll
        for (int mi = 0; mi < 4; ++mi)
#pragma unroll
            for (int ni = 0; ni < 4; ++ni)
                acc[mi][ni] = __builtin_amdgcn_mfma_f32_16x16x32_bf16(
                    aw[mi], bw[ni], acc[mi][ni], 0, 0, 0);
        __syncthreads();
    }

    const int lq4 = (lane >> 4) * 4;
    if (FINAL == 0) {
        bf16_t* Co = (bf16_t*)C;
#pragma unroll
        for (int mi = 0; mi < 4; ++mi)
#pragma unroll
            for (int ni = 0; ni < 4; ++ni) {
                const int col = n0 + wc + ni * 16 + lr;
                const float bcol = bias[col];
#pragma unroll
                for (int r = 0; r < 4; ++r) {
                    const int row = m0 + wr + mi * 16 + lq4 + r;
                    Co[(size_t)row * N + col] = (bf16_t)(acc[mi][ni][r] + bcol);
                }
            }
    } else {
        float* Co = (float*)C;
#pragma unroll
        for (int mi = 0; mi < 4; ++mi)
#pragma unroll
            for (int ni = 0; ni < 4; ++ni) {
                const int col = n0 + wc + ni * 16 + lr;
                const float bcol = bias[col];
#pragma unroll
                for (int r = 0; r < 4; ++r) {
                    const int row = m0 + wr + mi * 16 + lq4 + r;
                    const int b = row >> 10, s = row & 1023;
                    float v;
                    if (mask[b * SLEN + s]) v = acc[mi][ni][r] * 0.125f + bcol;
                    else v = trow[(size_t)b * DMODEL + col];
                    Co[(size_t)row * N + col] = v;
                }
            }
    }
}

// ---------------- W[b,h] = Kh_h^T @ Vh_h  (64x64 fp32, k-split x2) ----------------
__global__ __launch_bounds__(512) void compute_w(
    const bf16_t* __restrict__ Kh, const bf16_t* __restrict__ Vh,
    float* __restrict__ Wpart) {
    __shared__ float Ksf[64 * 64];
    __shared__ float Vsf[64 * 64];
    const int h = blockIdx.x;
    const int b = blockIdx.y;
    const int ks = blockIdx.z;
    const int tid = threadIdx.x;
    const int dd = tid & 63;
    const int eg = tid >> 6;           // 0..7 -> e = eg*8 + i
    const int srow = tid >> 3;         // 0..63
    const int sseg = (tid & 7) * 8;

    float acc[8] = {};
    for (int kc = 0; kc < 8; ++kc) {
        const int kbase = ks * 512 + kc * 64;
        const size_t roff = (size_t)(b * SLEN + kbase + srow) * DMODEL + h * HD + sseg;
        bf16x8 kv = *reinterpret_cast<const bf16x8*>(&Kh[roff]);
        bf16x8 vv = *reinterpret_cast<const bf16x8*>(&Vh[roff]);
#pragma unroll
        for (int j = 0; j < 8; ++j) {
            Ksf[srow * 64 + sseg + j] = (float)kv[j];
            Vsf[srow * 64 + sseg + j] = (float)vv[j];
        }
        __syncthreads();
#pragma unroll 4
        for (int kk = 0; kk < 64; ++kk) {
            const float vval = Vsf[kk * 64 + dd];
#pragma unroll
            for (int i = 0; i < 8; ++i)
                acc[i] += Ksf[kk * 64 + eg * 8 + i] * vval;  // Ksf read is wave-uniform (broadcast)
        }
        __syncthreads();
    }
    float* Wo = Wpart + (((size_t)ks * BSZ + b) * NH + h) * 4096;
#pragma unroll
    for (int i = 0; i < 8; ++i)
        Wo[(eg * 8 + i) * 64 + dd] = acc[i];
}

// ---------------- Spart[ks,b,d] = partial column-sum of Vh ----------------
__global__ __launch_bounds__(256) void colsum_v(
    const bf16_t* __restrict__ Vh, float* __restrict__ Spart) {
    const int dseg = blockIdx.x;   // 0..3
    const int b = blockIdx.y;      // 0..7
    const int ks = blockIdx.z;     // 0..7
    const int d = dseg * 256 + threadIdx.x;
    float acc = 0.f;
#pragma unroll 8
    for (int k = ks * 128; k < ks * 128 + 128; ++k)
        acc += (float)Vh[(size_t)(b * SLEN + k) * DMODEL + d];
    Spart[((size_t)ks * BSZ + b) * DMODEL + d] = acc;
}

// ---------------- t[b,j] = -1e9 * (S @ wo^T)[b,j] + bo[j]  (fp32 exact) ----------------
__global__ __launch_bounds__(256) void compute_t(
    const float* __restrict__ Spart, const float* __restrict__ wo,
    const float* __restrict__ bo, float* __restrict__ t) {
    __shared__ float Ss[DMODEL];
    const int b = blockIdx.x >> 8;          // 256 blocks per batch
    const int j0 = (blockIdx.x & 255) * 4;  // 4 j's per block (one per wave)
    const int tid = threadIdx.x;
#pragma unroll
    for (int i = 0; i < 4; ++i) {
        const int d = i * 256 + tid;
        float s = 0.f;
#pragma unroll
        for (int ks = 0; ks < 8; ++ks) s += Spart[((size_t)ks * BSZ + b) * DMODEL + d];
        Ss[d] = s;
    }
    __syncthreads();
    const int wave = tid >> 6, lane = tid & 63;
    const int j = j0 + wave;
    f32x4 acc = {};
#pragma unroll
    for (int it = 0; it < 4; ++it) {
        const int idx = it * 256 + lane * 4;
        const f32x4 wv = *reinterpret_cast<const f32x4*>(&wo[(size_t)j * DMODEL + idx]);
        const f32x4 sv = *reinterpret_cast<const f32x4*>(&Ss[idx]);
        acc += wv * sv;
    }
    float tot = acc[0] + acc[1] + acc[2] + acc[3];
#pragma unroll
    for (int off = 1; off < 64; off <<= 1) tot += __shfl_xor(tot, off, 64);
    if (lane == 0) t[(size_t)b * DMODEL + j] = -1e9f * tot + bo[j];
}

// ---------------- PT[b,j,h*64+e] = sum_dd W[b,h][e,dd] * wo[j,h*64+dd]  (bf16 out) ----------------
__global__ __launch_bounds__(256) void compute_pt(
    const float* __restrict__ Wpart, const float* __restrict__ wo,
    bf16_t* __restrict__ PT) {
    __shared__ float Ws[64 * 65];      // padded: bank-conflict-free on per-lane e reads
    __shared__ float Wos[128 * 64];
    const int jt = blockIdx.x;   // 0..7
    const int h = blockIdx.y;    // 0..15
    const int b = blockIdx.z;    // 0..7
    const int tid = threadIdx.x;
    const int j0 = jt * 128;
    const float* W0 = Wpart + (((size_t)0 * BSZ + b) * NH + h) * 4096;
    const float* W1 = Wpart + (((size_t)1 * BSZ + b) * NH + h) * 4096;
#pragma unroll
    for (int i = 0; i < 16; ++i) {
        const int idx = i * 256 + tid;
        Ws[(idx >> 6) * 65 + (idx & 63)] = W0[idx] + W1[idx];
    }
#pragma unroll
    for (int i = 0; i < 32; ++i) {
        const int idx = i * 256 + tid;
        Wos[idx] = wo[(size_t)(j0 + (idx >> 6)) * DMODEL + h * HD + (idx & 63)];
    }
    __syncthreads();
    const int e = tid & 63;
    const int jb = tid >> 6;   // 0..3
    for (int jj2 = 0; jj2 < 32; ++jj2) {
        const int jj = jb * 32 + jj2;
        float acc = 0.f;
#pragma unroll
        for (int dd = 0; dd < 64; ++dd)
            acc += Wos[jj * 64 + dd] * Ws[e * 65 + dd];   // Wos wave-uniform; Ws conflict-free
        PT[((size_t)b * SLEN + j0 + jj) * DMODEL + h * HD + e] = (bf16_t)acc;
    }
}

extern "C" void kernel_launch(void* const* d_in, const int* in_sizes, int n_in,
                              void* d_out, int out_size, void* d_ws, size_t ws_size,
                              hipStream_t stream) {
    const float* q  = (const float*)d_in[0];
    const float* k  = (const float*)d_in[1];
    const float* v  = (const float*)d_in[2];
    const int* mask = (const int*)d_in[3];
    const float* wq = (const float*)d_in[4];
    const float* bq = (const float*)d_in[5];
    const float* wk = (const float*)d_in[6];
    const float* bk = (const float*)d_in[7];
    const float* wv = (const float*)d_in[8];
    const float* bv = (const float*)d_in[9];
    const float* wo = (const float*)d_in[10];
    const float* bo = (const float*)d_in[11];

    char* ws = (char*)d_ws;
    const size_t SZ_ACT = (size_t)MROWS * DMODEL * 2;   // 16 MB (bf16 activations)
    const size_t SZ_W = (size_t)DMODEL * DMODEL * 2;    // 2 MB  (bf16 weights)
    // buffer time-sharing (total ~74.6 MB):
    bf16_t* buf0 = (bf16_t*)(ws);                 // q_bf16, later Kh
    bf16_t* buf1 = (bf16_t*)(ws + SZ_ACT);        // k_bf16, later Vh
    bf16_t* buf2 = (bf16_t*)(ws + 2 * SZ_ACT);    // v_bf16, later PT
    bf16_t* Qh   = (bf16_t*)(ws + 3 * SZ_ACT);
    bf16_t* wqb  = (bf16_t*)(ws + 4 * SZ_ACT);
    bf16_t* wkb  = (bf16_t*)(ws + 4 * SZ_ACT + SZ_W);
    bf16_t* wvb  = (bf16_t*)(ws + 4 * SZ_ACT + 2 * SZ_W);
    float* Wpart = (float*)(ws + 4 * SZ_ACT + 3 * SZ_W);            // 2*8*16*4096*4 = 4 MB
    float* Spart = (float*)((char*)Wpart + (size_t)2 * 8 * 16 * 4096 * 4);  // 256 KB
    float* trow  = (float*)((char*)Spart + (size_t)8 * 8 * 1024 * 4);       // 32 KB

    const int n4a = MROWS * DMODEL / 4;    // 2M float4s
    const int n4w = DMODEL * DMODEL / 4;   // 256K float4s
    cvt_f32_to_bf16<<<dim3(n4a / 256), 256, 0, stream>>>(q, buf0, n4a);
    cvt_f32_to_bf16<<<dim3(n4a / 256), 256, 0, stream>>>(k, buf1, n4a);
    cvt_f32_to_bf16<<<dim3(n4a / 256), 256, 0, stream>>>(v, buf2, n4a);
    cvt_f32_to_bf16<<<dim3(n4w / 256), 256, 0, stream>>>(wq, wqb, n4w);
    cvt_f32_to_bf16<<<dim3(n4w / 256), 256, 0, stream>>>(wk, wkb, n4w);
    cvt_f32_to_bf16<<<dim3(n4w / 256), 256, 0, stream>>>(wv, wvb, n4w);

    const dim3 gg(DMODEL / 128, MROWS / 128);  // (8, 64)
    gemm_bt<0><<<gg, 256, 0, stream>>>(buf0, wqb, Qh,   bq, nullptr, nullptr, MROWS, DMODEL, DMODEL, 0);
    gemm_bt<0><<<gg, 256, 0, stream>>>(buf1, wkb, buf0, bk, nullptr, nullptr, MROWS, DMODEL, DMODEL, 0); // Kh
    gemm_bt<0><<<gg, 256, 0, stream>>>(buf2, wvb, buf1, bv, nullptr, nullptr, MROWS, DMODEL, DMODEL, 0); // Vh

    compute_w<<<dim3(NH, BSZ, 2), 512, 0, stream>>>(buf0, buf1, Wpart);
    colsum_v<<<dim3(4, BSZ, 8), 256, 0, stream>>>(buf1, Spart);
    compute_t<<<dim3(2048), 256, 0, stream>>>(Spart, wo, bo, trow);
    compute_pt<<<dim3(8, NH, BSZ), 256, 0, stream>>>(Wpart, wo, buf2);  // PT

    gemm_bt<1><<<gg, 256, 0, stream>>>(Qh, buf2, d_out, bo, trow, mask,
                                       MROWS, DMODEL, DMODEL, SLEN * DMODEL);
}

// Round 2
// 350.943 us; speedup vs baseline: 1.0949x; 1.0949x over previous
//
#include <hip/hip_runtime.h>
#include <hip/hip_bf16.h>
#include <stdint.h>

// (BS, SL, D, H) = (8, 1024, 1024, 16), DK = 64.
#define BSZ 8
#define SLEN 1024
#define DMODEL 1024
#define NH 16
#define HD 64
#define MROWS (BSZ * SLEN)  // 8192
#define NT 16               // K tiles of 64 (K = DMODEL = 1024)

typedef __bf16 bf16_t;
typedef __bf16 bf16x8 __attribute__((ext_vector_type(8)));
typedef __bf16 bf16x4 __attribute__((ext_vector_type(4)));
typedef float f32x4 __attribute__((ext_vector_type(4)));

__device__ __forceinline__ void gload_lds16(const void* g, void* l) {
    __builtin_amdgcn_global_load_lds(
        (const __attribute__((address_space(1))) unsigned int*)g,
        (__attribute__((address_space(3))) unsigned int*)l, 16, 0, 0);
}

// ---------------- fp32 -> bf16 convert, 3 tensors per launch ----------------
__global__ __launch_bounds__(256) void cvt3(
    const float* __restrict__ s0, const float* __restrict__ s1, const float* __restrict__ s2,
    bf16_t* __restrict__ o0, bf16_t* __restrict__ o1, bf16_t* __restrict__ o2, int n4) {
    const float* s = s0; bf16_t* d = o0;
    if (blockIdx.y == 1) { s = s1; d = o1; }
    else if (blockIdx.y == 2) { s = s2; d = o2; }
    int i = blockIdx.x * blockDim.x + threadIdx.x;
    if (i >= n4) return;
    const float4 v = reinterpret_cast<const float4*>(s)[i];
    bf16x4 o;
    o[0] = (bf16_t)v.x; o[1] = (bf16_t)v.y; o[2] = (bf16_t)v.z; o[3] = (bf16_t)v.w;
    reinterpret_cast<bf16x4*>(d)[i] = o;
}

// ---------------- 256x256 BK=64 8-wave pipelined GEMM, C = A @ B^T ----------------
// A: M x 1024 row-major bf16.  B: 1024 x 1024 row-major bf16 (per-batch for FINAL).
// 4 phases/K-tile, counted vmcnt(4) at ph0/ph2 only, K-split LDS halves with
// per-row granule-rotation layout (bank-conflict-free b128 fragment reads).
__device__ __forceinline__ void mfma_quad(f32x4 (&acc)[8][4], int mb,
                                          const bf16x8 (&afr)[4], const bf16x8 (&bfr)[4]) {
    __builtin_amdgcn_s_setprio(1);
#pragma unroll
    for (int m = 0; m < 4; ++m)
#pragma unroll
        for (int n = 0; n < 4; ++n)
            acc[mb + m][n] = __builtin_amdgcn_mfma_f32_16x16x32_bf16(
                afr[m], bfr[n], acc[mb + m][n], 0, 0, 0);
    __builtin_amdgcn_s_setprio(0);
}

template <int FINAL>
__global__ __launch_bounds__(512, 2) void gemm256(
    const bf16_t* __restrict__ A0, const bf16_t* __restrict__ B0p, void* __restrict__ C0, const float* __restrict__ bias0,
    const bf16_t* __restrict__ A1, const bf16_t* __restrict__ B1p, void* __restrict__ C1, const float* __restrict__ bias1,
    const bf16_t* __restrict__ A2, const bf16_t* __restrict__ B2p, void* __restrict__ C2, const float* __restrict__ bias2,
    const float* __restrict__ trow, const int* __restrict__ mask) {
    // [dbuf*2 + khalf][256 rows * 32 k-cols]; 64 KB each operand, 128 KB total.
    __shared__ __align__(16) bf16_t As[4][256 * 32];
    __shared__ __align__(16) bf16_t Bs[4][256 * 32];
    const int tid = threadIdx.x;
    const int lane = tid & 63, wave = tid >> 6;
    const int wm = wave >> 2, wn = wave & 3;     // 2 x 4 wave grid; wave tile 128x64
    const int lr = lane & 15, g = lane >> 4;     // fragment row, k-granule (16B)

    const bf16_t* A = A0; const bf16_t* B = B0p; void* C = C0; const float* bias = bias0;
    if (blockIdx.z == 1) { A = A1; B = B1p; C = C1; bias = bias1; }
    else if (blockIdx.z == 2) { A = A2; B = B2p; C = C2; bias = bias2; }

    const int m0 = blockIdx.y * 256;
    const int n0 = blockIdx.x * 256;
    if (FINAL) B += (size_t)(m0 >> 10) * SLEN * DMODEL;  // per-batch B panel

    // staging: half = 256 rows x 32 cols = 16 KB = 1024 granules; 2 chunks/thread.
    // LDS granule q holds global (row = q>>2, g = ((q&3) - (row>>1)) & 3).
    const int q0 = wave * 64 + lane, q1 = 512 + q0;
    const int row0 = q0 >> 2, row1 = q1 >> 2;
    const int gl0 = ((q0 & 3) - (row0 >> 1)) & 3;
    const int gl1 = ((q1 & 3) - (row1 >> 1)) & 3;
    const int sOfs0 = row0 * DMODEL + gl0 * 8;
    const int sOfs1 = row1 * DMODEL + gl1 * 8;
    const bf16_t* Ag = A + (size_t)m0 * DMODEL;
    const bf16_t* Bg = B + (size_t)n0 * DMODEL;
    char* const AsB = (char*)&As[0][0];
    char* const BsB = (char*)&Bs[0][0];
    const int d0 = q0 * 16, d1 = q1 * 16;

    // fragment read byte offsets within a half: r*64 + rotated granule*16
    int aoff[8], boff[4];
#pragma unroll
    for (int mi = 0; mi < 8; ++mi) {
        const int r = wm * 128 + mi * 16 + lr;
        aoff[mi] = r * 64 + (((g + (r >> 1)) & 3) << 4);
    }
#pragma unroll
    for (int ni = 0; ni < 4; ++ni) {
        const int r = wn * 64 + ni * 16 + lr;
        boff[ni] = r * 64 + (((g + (r >> 1)) & 3) << 4);
    }

    f32x4 acc[8][4] = {};

    // prologue: stage tile 0 in steady-state order (Ak0, Bk0, Ak1, Bk1)
    gload_lds16(Ag + sOfs0, AsB + d0);
    gload_lds16(Ag + sOfs1, AsB + d1);
    gload_lds16(Bg + sOfs0, BsB + d0);
    gload_lds16(Bg + sOfs1, BsB + d1);
    gload_lds16(Ag + sOfs0 + 32, AsB + 16384 + d0);
    gload_lds16(Ag + sOfs1 + 32, AsB + 16384 + d1);
    gload_lds16(Bg + sOfs0 + 32, BsB + 16384 + d0);
    gload_lds16(Bg + sOfs1 + 32, BsB + 16384 + d1);

    for (int t = 0; t < NT; ++t) {
        const int cur = t & 1, nxt = cur ^ 1;
        const int kn = ((t + 1 < NT) ? (t + 1) : 0) * 64;  // clamped: uniform issue count
        const char* Ac0 = AsB + cur * 32768;
        const char* Ac1 = Ac0 + 16384;
        const char* Bc0 = BsB + cur * 32768;
        const char* Bc1 = Bc0 + 16384;
        char* An0 = AsB + nxt * 32768; char* An1 = An0 + 16384;
        char* Bn0 = BsB + nxt * 32768; char* Bn1 = Bn0 + 16384;
        bf16x8 afr[4], bfr[4];

        // ---- ph0: kh0, mi 0-3 ---- (wait: Ak0,Bk0 of tile t staged 4 phases ago)
        asm volatile("s_waitcnt vmcnt(4)" ::: "memory");
        __builtin_amdgcn_s_barrier();
        __builtin_amdgcn_sched_barrier(0);
        gload_lds16(Ag + sOfs0 + kn, An0 + d0);
        gload_lds16(Ag + sOfs1 + kn, An0 + d1);
#pragma unroll
        for (int i = 0; i < 4; ++i) bfr[i] = *reinterpret_cast<const bf16x8*>(Bc0 + boff[i]);
#pragma unroll
        for (int i = 0; i < 4; ++i) afr[i] = *reinterpret_cast<const bf16x8*>(Ac0 + aoff[i]);
        mfma_quad(acc, 0, afr, bfr);

        // ---- ph1: kh0, mi 4-7 ----
        gload_lds16(Bg + sOfs0 + kn, Bn0 + d0);
        gload_lds16(Bg + sOfs1 + kn, Bn0 + d1);
#pragma unroll
        for (int i = 0; i < 4; ++i) afr[i] = *reinterpret_cast<const bf16x8*>(Ac0 + aoff[4 + i]);
        mfma_quad(acc, 4, afr, bfr);

        // ---- ph2: kh1, mi 0-3 ---- (wait: Ak1,Bk1 of tile t)
        asm volatile("s_waitcnt vmcnt(4)" ::: "memory");
        __builtin_amdgcn_s_barrier();
        __builtin_amdgcn_sched_barrier(0);
        gload_lds16(Ag + sOfs0 + kn + 32, An1 + d0);
        gload_lds16(Ag + sOfs1 + kn + 32, An1 + d1);
#pragma unroll
        for (int i = 0; i < 4; ++i) bfr[i] = *reinterpret_cast<const bf16x8*>(Bc1 + boff[i]);
#pragma unroll
        for (int i = 0; i < 4; ++i) afr[i] = *reinterpret_cast<const bf16x8*>(Ac1 + aoff[i]);
        mfma_quad(acc, 0, afr, bfr);

        // ---- ph3: kh1, mi 4-7 ----
        gload_lds16(Bg + sOfs0 + kn + 32, Bn1 + d0);
        gload_lds16(Bg + sOfs1 + kn + 32, Bn1 + d1);
#pragma unroll
        for (int i = 0; i < 4; ++i) afr[i] = *reinterpret_cast<const bf16x8*>(Ac1 + aoff[4 + i]);
        mfma_quad(acc, 4, afr, bfr);
    }

    // epilogue
    const int lq4 = g * 4;
    if (FINAL == 0) {
        bf16_t* Co = (bf16_t*)C;
#pragma unroll
        for (int mi = 0; mi < 8; ++mi)
#pragma unroll
            for (int ni = 0; ni < 4; ++ni) {
                const int col = n0 + wn * 64 + ni * 16 + lr;
                const float bcol = bias[col];
#pragma unroll
                for (int r = 0; r < 4; ++r) {
                    const int row = m0 + wm * 128 + mi * 16 + lq4 + r;
                    Co[(size_t)row * DMODEL + col] = (bf16_t)(acc[mi][ni][r] + bcol);
                }
            }
    } else {
        float* Co = (float*)C;
#pragma unroll
        for (int mi = 0; mi < 8; ++mi)
#pragma unroll
            for (int ni = 0; ni < 4; ++ni) {
                const int col = n0 + wn * 64 + ni * 16 + lr;
                const float bcol = bias[col];
#pragma unroll
                for (int r = 0; r < 4; ++r) {
                    const int row = m0 + wm * 128 + mi * 16 + lq4 + r;
                    const int b = row >> 10, s = row & 1023;
                    float v;
                    if (mask[b * SLEN + s]) v = acc[mi][ni][r] * 0.125f + bcol;
                    else v = trow[(size_t)b * DMODEL + col];
                    Co[(size_t)row * DMODEL + col] = v;
                }
            }
    }
}

// ---------------- W[b,h] = Kh_h^T @ Vh_h  (64x64 fp32, k-split x2) ----------------
__global__ __launch_bounds__(512) void compute_w(
    const bf16_t* __restrict__ Kh, const bf16_t* __restrict__ Vh,
    float* __restrict__ Wpart) {
    __shared__ float Ksf[64 * 64];
    __shared__ float Vsf[64 * 64];
    const int h = blockIdx.x;
    const int b = blockIdx.y;
    const int ks = blockIdx.z;
    const int tid = threadIdx.x;
    const int dd = tid & 63;
    const int eg = tid >> 6;
    const int srow = tid >> 3;
    const int sseg = (tid & 7) * 8;

    float acc[8] = {};
    for (int kc = 0; kc < 8; ++kc) {
        const int kbase = ks * 512 + kc * 64;
        const size_t roff = (size_t)(b * SLEN + kbase + srow) * DMODEL + h * HD + sseg;
        bf16x8 kv = *reinterpret_cast<const bf16x8*>(&Kh[roff]);
        bf16x8 vv = *reinterpret_cast<const bf16x8*>(&Vh[roff]);
#pragma unroll
        for (int j = 0; j < 8; ++j) {
            Ksf[srow * 64 + sseg + j] = (float)kv[j];
            Vsf[srow * 64 + sseg + j] = (float)vv[j];
        }
        __syncthreads();
#pragma unroll 4
        for (int kk = 0; kk < 64; ++kk) {
            const float vval = Vsf[kk * 64 + dd];
#pragma unroll
            for (int i = 0; i < 8; ++i)
                acc[i] += Ksf[kk * 64 + eg * 8 + i] * vval;
        }
        __syncthreads();
    }
    float* Wo = Wpart + (((size_t)ks * BSZ + b) * NH + h) * 4096;
#pragma unroll
    for (int i = 0; i < 8; ++i)
        Wo[(eg * 8 + i) * 64 + dd] = acc[i];
}

// ---------------- Spart[ks,b,d] = partial column-sum of Vh ----------------
__global__ __launch_bounds__(256) void colsum_v(
    const bf16_t* __restrict__ Vh, float* __restrict__ Spart) {
    const int dseg = blockIdx.x;
    const int b = blockIdx.y;
    const int ks = blockIdx.z;
    const int d = dseg * 256 + threadIdx.x;
    float acc = 0.f;
#pragma unroll 8
    for (int k = ks * 128; k < ks * 128 + 128; ++k)
        acc += (float)Vh[(size_t)(b * SLEN + k) * DMODEL + d];
    Spart[((size_t)ks * BSZ + b) * DMODEL + d] = acc;
}

// ---------------- t[b,j] = -1e9 * (S @ wo^T)[b,j] + bo[j] ----------------
__global__ __launch_bounds__(256) void compute_t(
    const float* __restrict__ Spart, const float* __restrict__ wo,
    const float* __restrict__ bo, float* __restrict__ t) {
    __shared__ float Ss[DMODEL];
    const int b = blockIdx.x >> 8;
    const int j0 = (blockIdx.x & 255) * 4;
    const int tid = threadIdx.x;
#pragma unroll
    for (int i = 0; i < 4; ++i) {
        const int d = i * 256 + tid;
        float s = 0.f;
#pragma unroll
        for (int ks = 0; ks < 8; ++ks) s += Spart[((size_t)ks * BSZ + b) * DMODEL + d];
        Ss[d] = s;
    }
    __syncthreads();
    const int wave = tid >> 6, lane = tid & 63;
    const int j = j0 + wave;
    f32x4 acc = {};
#pragma unroll
    for (int it = 0; it < 4; ++it) {
        const int idx = it * 256 + lane * 4;
        const f32x4 wv = *reinterpret_cast<const f32x4*>(&wo[(size_t)j * DMODEL + idx]);
        const f32x4 sv = *reinterpret_cast<const f32x4*>(&Ss[idx]);
        acc += wv * sv;
    }
    float tot = acc[0] + acc[1] + acc[2] + acc[3];
#pragma unroll
    for (int off = 1; off < 64; off <<= 1) tot += __shfl_xor(tot, off, 64);
    if (lane == 0) t[(size_t)b * DMODEL + j] = -1e9f * tot + bo[j];
}

// ---------------- PT[b,j,h*64+e] = sum_dd W[b,h][e,dd] * wo[j,h*64+dd] ----------------
__global__ __launch_bounds__(256) void compute_pt(
    const float* __restrict__ Wpart, const float* __restrict__ wo,
    bf16_t* __restrict__ PT) {
    __shared__ float Ws[64 * 65];
    __shared__ float Wos[128 * 64];
    const int jt = blockIdx.x;
    const int h = blockIdx.y;
    const int b = blockIdx.z;
    const int tid = threadIdx.x;
    const int j0 = jt * 128;
    const float* W0 = Wpart + (((size_t)0 * BSZ + b) * NH + h) * 4096;
    const float* W1 = Wpart + (((size_t)1 * BSZ + b) * NH + h) * 4096;
#pragma unroll
    for (int i = 0; i < 16; ++i) {
        const int idx = i * 256 + tid;
        Ws[(idx >> 6) * 65 + (idx & 63)] = W0[idx] + W1[idx];
    }
#pragma unroll
    for (int i = 0; i < 32; ++i) {
        const int idx = i * 256 + tid;
        Wos[idx] = wo[(size_t)(j0 + (idx >> 6)) * DMODEL + h * HD + (idx & 63)];
    }
    __syncthreads();
    const int e = tid & 63;
    const int jb = tid >> 6;
    for (int jj2 = 0; jj2 < 32; ++jj2) {
        const int jj = jb * 32 + jj2;
        float acc = 0.f;
#pragma unroll
        for (int dd = 0; dd < 64; ++dd)
            acc += Wos[jj * 64 + dd] * Ws[e * 65 + dd];
        PT[((size_t)b * SLEN + j0 + jj) * DMODEL + h * HD + e] = (bf16_t)acc;
    }
}

extern "C" void kernel_launch(void* const* d_in, const int* in_sizes, int n_in,
                              void* d_out, int out_size, void* d_ws, size_t ws_size,
                              hipStream_t stream) {
    const float* q  = (const float*)d_in[0];
    const float* k  = (const float*)d_in[1];
    const float* v  = (const float*)d_in[2];
    const int* mask = (const int*)d_in[3];
    const float* wq = (const float*)d_in[4];
    const float* bq = (const float*)d_in[5];
    const float* wk = (const float*)d_in[6];
    const float* bk = (const float*)d_in[7];
    const float* wv = (const float*)d_in[8];
    const float* bv = (const float*)d_in[9];
    const float* wo = (const float*)d_in[10];
    const float* bo = (const float*)d_in[11];

    char* ws = (char*)d_ws;
    const size_t SZ_ACT = (size_t)MROWS * DMODEL * 2;   // 16 MB
    const size_t SZ_W = (size_t)DMODEL * DMODEL * 2;    // 2 MB
    const size_t SZ_WPART = (size_t)2 * 8 * 16 * 4096 * 4;  // 4 MB
    const size_t SZ_SPART = (size_t)8 * 8 * 1024 * 4;
    const size_t SZ_TROW = (size_t)8 * 1024 * 4;
    const size_t need_roomy = 6 * SZ_ACT + 3 * SZ_W + SZ_WPART + SZ_SPART + SZ_TROW;
    const bool roomy = ws_size >= need_roomy;

    bf16_t* qb = (bf16_t*)(ws);
    bf16_t* kb = (bf16_t*)(ws + SZ_ACT);
    bf16_t* vb = (bf16_t*)(ws + 2 * SZ_ACT);
    bf16_t* Qh = (bf16_t*)(ws + 3 * SZ_ACT);
    bf16_t *Kh, *Vh, *PT;
    char* tail;
    if (roomy) {
        Kh = (bf16_t*)(ws + 4 * SZ_ACT);
        Vh = (bf16_t*)(ws + 5 * SZ_ACT);
        PT = qb;                       // q bf16 dead after projections
        tail = ws + 6 * SZ_ACT;
    } else {
        Kh = qb; Vh = kb; PT = vb;     // sequential aliasing (round-0 layout)
        tail = ws + 4 * SZ_ACT;
    }
    bf16_t* wqb = (bf16_t*)(tail);
    bf16_t* wkb = (bf16_t*)(tail + SZ_W);
    bf16_t* wvb = (bf16_t*)(tail + 2 * SZ_W);
    float* Wpart = (float*)(tail + 3 * SZ_W);
    float* Spart = (float*)(tail + 3 * SZ_W + SZ_WPART);
    float* trow  = (float*)(tail + 3 * SZ_W + SZ_WPART + SZ_SPART);

    const int n4a = MROWS * DMODEL / 4;
    const int n4w = DMODEL * DMODEL / 4;
    cvt3<<<dim3(n4a / 256, 3), 256, 0, stream>>>(q, k, v, qb, kb, vb, n4a);
    cvt3<<<dim3(n4w / 256, 3), 256, 0, stream>>>(wq, wk, wv, wqb, wkb, wvb, n4w);

    if (roomy) {
        gemm256<0><<<dim3(4, 32, 3), 512, 0, stream>>>(
            qb, wqb, Qh, bq, kb, wkb, Kh, bk, vb, wvb, Vh, bv, nullptr, nullptr);
    } else {
        gemm256<0><<<dim3(4, 32, 1), 512, 0, stream>>>(
            qb, wqb, Qh, bq, qb, wqb, Qh, bq, qb, wqb, Qh, bq, nullptr, nullptr);
        gemm256<0><<<dim3(4, 32, 1), 512, 0, stream>>>(
            kb, wkb, Kh, bk, kb, wkb, Kh, bk, kb, wkb, Kh, bk, nullptr, nullptr);
        gemm256<0><<<dim3(4, 32, 1), 512, 0, stream>>>(
            vb, wvb, Vh, bv, vb, wvb, Vh, bv, vb, wvb, Vh, bv, nullptr, nullptr);
    }

    compute_w<<<dim3(NH, BSZ, 2), 512, 0, stream>>>(Kh, Vh, Wpart);
    colsum_v<<<dim3(4, BSZ, 8), 256, 0, stream>>>(Vh, Spart);
    compute_t<<<dim3(2048), 256, 0, stream>>>(Spart, wo, bo, trow);
    compute_pt<<<dim3(8, NH, BSZ), 256, 0, stream>>>(Wpart, wo, PT);

    gemm256<1><<<dim3(4, 32, 1), 512, 0, stream>>>(
        Qh, PT, d_out, bo, Qh, PT, d_out, bo, Qh, PT, d_out, bo, trow, mask);
}

// Round 4
// 316.049 us; speedup vs baseline: 1.2158x; 1.1104x over previous
//
#include <hip/hip_runtime.h>
#include <hip/hip_bf16.h>
#include <stdint.h>

// (BS, SL, D, H) = (8, 1024, 1024, 16), DK = 64.
#define BATCH 8
#define SLEN 1024
#define DMODEL 1024
#define NH 16
#define HD 64
#define MROWS (BATCH * SLEN)  // 8192
#define NT 16                 // K tiles of 64 (K = 1024)

typedef __bf16 bf16_t;
typedef __bf16 bf16x8 __attribute__((ext_vector_type(8)));
typedef __bf16 bf16x4 __attribute__((ext_vector_type(4)));
typedef float f32x4 __attribute__((ext_vector_type(4)));

__device__ __forceinline__ void gload_lds16(const void* g, void* l) {
    __builtin_amdgcn_global_load_lds(
        (const __attribute__((address_space(1))) unsigned int*)g,
        (__attribute__((address_space(3))) unsigned int*)l, 16, 0, 0);
}

// ---------------- fp32 -> bf16 convert, 7 tensors in one launch ----------------
__global__ __launch_bounds__(256) void cvt7(
    const float* __restrict__ s0, const float* __restrict__ s1, const float* __restrict__ s2,
    const float* __restrict__ s3, const float* __restrict__ s4, const float* __restrict__ s5,
    const float* __restrict__ s6,
    bf16_t* __restrict__ o0, bf16_t* __restrict__ o1, bf16_t* __restrict__ o2,
    bf16_t* __restrict__ o3, bf16_t* __restrict__ o4, bf16_t* __restrict__ o5,
    bf16_t* __restrict__ o6, int n4a, int n4w) {
    const float* srcs[7] = {s0, s1, s2, s3, s4, s5, s6};
    bf16_t* dsts[7] = {o0, o1, o2, o3, o4, o5, o6};
    const int y = blockIdx.y;
    const int n4 = (y < 3) ? n4a : n4w;
    int i = blockIdx.x * blockDim.x + threadIdx.x;
    if (i >= n4) return;
    const float4 v = reinterpret_cast<const float4*>(srcs[y])[i];
    bf16x4 o;
    o[0] = (bf16_t)v.x; o[1] = (bf16_t)v.y; o[2] = (bf16_t)v.z; o[3] = (bf16_t)v.w;
    reinterpret_cast<bf16x4*>(dsts[y])[i] = o;
}

// ---------------- generic 256x128 BK=64 8-wave pipelined GEMM, C = A @ B^T ----------------
// All matrices row-major with row stride 1024 (K=1024). Per-slice M,N; brow picks
// bias-by-row (transposed outputs). FINAL==1: fp32 out, mask/trow epilogue, B per-batch.
struct Slice {
    const bf16_t* A; const bf16_t* B; void* C; const float* bias; int M, N, brow;
};

#define AHALF 16384   // bytes: 256 rows x 32 cols bf16
#define BHALF 8192    // bytes: 128 rows x 32 cols bf16

__device__ __forceinline__ void mfma8(f32x4 (&acc)[8][2], int mb,
                                      const bf16x8 (&afr)[4], const bf16x8 (&bfr)[2]) {
    __builtin_amdgcn_s_setprio(1);
#pragma unroll
    for (int m = 0; m < 4; ++m)
#pragma unroll
        for (int n = 0; n < 2; ++n)
            acc[mb + m][n] = __builtin_amdgcn_mfma_f32_16x16x32_bf16(
                afr[m], bfr[n], acc[mb + m][n], 0, 0, 0);
    __builtin_amdgcn_s_setprio(0);
}

template <int FINAL>
__global__ __launch_bounds__(512, 2) void gemm_tiled(
    Slice s0, Slice s1, Slice s2,
    const float* __restrict__ trow, const int* __restrict__ mask) {
    // LDS: A 4 x 16KB (dbuf x khalf) + B 4 x 8KB = 96KB.
    __shared__ __align__(16) char As[4 * AHALF];
    __shared__ __align__(16) char Bs[4 * BHALF];
    const int tid = threadIdx.x;
    const int lane = tid & 63, wave = tid >> 6;
    const int wm = wave >> 2, wn = wave & 3;  // 2M x 4N waves; wave tile 128x32
    const int lr = lane & 15, g = lane >> 4;

    // bijective XCD swizzle (gridDim.x % 8 == 0)
    const int nb = gridDim.x;
    const int bid = blockIdx.x;
    const int swz = (bid & 7) * (nb >> 3) + (bid >> 3);
    const int sl = swz >> 8;        // 256 blocks per slice
    const int w = swz & 255;
    Slice S = (sl == 0) ? s0 : (sl == 1) ? s1 : s2;
    const int ntn = S.N >> 7;       // n-tiles of 128
    const int ty = w / ntn, tx = w - ty * ntn;
    const int m0 = ty * 256, n0 = tx * 128;
    const bf16_t* A = S.A;
    const bf16_t* B = S.B;
    if (FINAL) B += (size_t)(m0 >> 10) * SLEN * DMODEL;  // per-batch B panel

    // staging: A half = 1024 granules (2/thread), B half = 512 (1/thread).
    // LDS granule q holds source granule gl = ((q&3) - (row>>1)) & 3 of row q>>2.
    const int qa0 = tid, qa1 = tid + 512, qb = tid;
    const int rA0 = qa0 >> 2, rA1 = qa1 >> 2, rB = qb >> 2;
    const int glA0 = ((qa0 & 3) - (rA0 >> 1)) & 3;
    const int glA1 = ((qa1 & 3) - (rA1 >> 1)) & 3;
    const int glB  = ((qb  & 3) - (rB  >> 1)) & 3;
    const bf16_t* Ag0 = A + (size_t)(m0 + rA0) * DMODEL + glA0 * 8;
    const bf16_t* Ag1 = A + (size_t)(m0 + rA1) * DMODEL + glA1 * 8;
    const bf16_t* Bg  = B + (size_t)(n0 + rB)  * DMODEL + glB  * 8;
    const int dA0 = qa0 * 16, dA1 = qa1 * 16, dB = qb * 16;

    // fragment byte offsets within a half (row stride 64B, granule rotation)
    int aoff[8], boff[2];
#pragma unroll
    for (int mi = 0; mi < 8; ++mi) {
        const int r = wm * 128 + mi * 16 + lr;
        aoff[mi] = r * 64 + (((g + (r >> 1)) & 3) << 4);
    }
#pragma unroll
    for (int ni = 0; ni < 2; ++ni) {
        const int r = wn * 32 + ni * 16 + lr;
        boff[ni] = r * 64 + (((g + (r >> 1)) & 3) << 4);
    }

    f32x4 acc[8][2] = {};

    // prologue: tile 0 in steady-state order (A-h0 x2, B-h0, A-h1 x2, B-h1)
    gload_lds16(Ag0, As + dA0);
    gload_lds16(Ag1, As + dA1);
    gload_lds16(Bg,  Bs + dB);
    gload_lds16(Ag0 + 32, As + AHALF + dA0);
    gload_lds16(Ag1 + 32, As + AHALF + dA1);
    gload_lds16(Bg  + 32, Bs + BHALF + dB);

    for (int t = 0; t < NT; ++t) {
        const int cur = t & 1, nxt = cur ^ 1;
        const int kn = ((t + 1 < NT) ? (t + 1) : 0) * 64;  // clamped: uniform issue count
        const char* Ac0 = As + cur * 2 * AHALF;
        const char* Ac1 = Ac0 + AHALF;
        const char* Bc0 = Bs + cur * 2 * BHALF;
        const char* Bc1 = Bc0 + BHALF;
        char* An0 = As + nxt * 2 * AHALF; char* An1 = An0 + AHALF;
        char* Bn0 = Bs + nxt * 2 * BHALF; char* Bn1 = Bn0 + BHALF;
        bf16x8 afr[4], bfr[2];

        // ---- ph0: kh0, mi 0-3 ---- (A-h0,B-h0 of tile t are oldest 3 loads)
        asm volatile("s_waitcnt vmcnt(3)" ::: "memory");
        __builtin_amdgcn_s_barrier();
        __builtin_amdgcn_sched_barrier(0);
        gload_lds16(Ag0 + kn, An0 + dA0);
        gload_lds16(Ag1 + kn, An0 + dA1);
#pragma unroll
        for (int i = 0; i < 2; ++i) bfr[i] = *reinterpret_cast<const bf16x8*>(Bc0 + boff[i]);
#pragma unroll
        for (int i = 0; i < 4; ++i) afr[i] = *reinterpret_cast<const bf16x8*>(Ac0 + aoff[i]);
        mfma8(acc, 0, afr, bfr);

        // ---- ph1: kh0, mi 4-7 ----
        gload_lds16(Bg + kn, Bn0 + dB);
#pragma unroll
        for (int i = 0; i < 4; ++i) afr[i] = *reinterpret_cast<const bf16x8*>(Ac0 + aoff[4 + i]);
        mfma8(acc, 4, afr, bfr);

        // ---- ph2: kh1, mi 0-3 ----
        asm volatile("s_waitcnt vmcnt(3)" ::: "memory");
        __builtin_amdgcn_s_barrier();
        __builtin_amdgcn_sched_barrier(0);
        gload_lds16(Ag0 + kn + 32, An1 + dA0);
        gload_lds16(Ag1 + kn + 32, An1 + dA1);
#pragma unroll
        for (int i = 0; i < 2; ++i) bfr[i] = *reinterpret_cast<const bf16x8*>(Bc1 + boff[i]);
#pragma unroll
        for (int i = 0; i < 4; ++i) afr[i] = *reinterpret_cast<const bf16x8*>(Ac1 + aoff[i]);
        mfma8(acc, 0, afr, bfr);

        // ---- ph3: kh1, mi 4-7 ----
        gload_lds16(Bg + kn + 32, Bn1 + dB);
#pragma unroll
        for (int i = 0; i < 4; ++i) afr[i] = *reinterpret_cast<const bf16x8*>(Ac1 + aoff[4 + i]);
        mfma8(acc, 4, afr, bfr);
    }

    // epilogue
    const int N = S.N;
    if (FINAL == 0) {
        bf16_t* Co = (bf16_t*)S.C;
#pragma unroll
        for (int mi = 0; mi < 8; ++mi)
#pragma unroll
            for (int ni = 0; ni < 2; ++ni) {
                const int col = n0 + wn * 32 + ni * 16 + lr;
#pragma unroll
                for (int r = 0; r < 4; ++r) {
                    const int row = m0 + wm * 128 + mi * 16 + g * 4 + r;
                    const float bv = S.bias[S.brow ? row : col];
                    Co[(size_t)row * N + col] = (bf16_t)(acc[mi][ni][r] + bv);
                }
            }
    } else {
        float* Co = (float*)S.C;
#pragma unroll
        for (int mi = 0; mi < 8; ++mi)
#pragma unroll
            for (int ni = 0; ni < 2; ++ni) {
                const int col = n0 + wn * 32 + ni * 16 + lr;
                const float bcol = S.bias[col];
#pragma unroll
                for (int r = 0; r < 4; ++r) {
                    const int row = m0 + wm * 128 + mi * 16 + g * 4 + r;
                    const int b = row >> 10, s = row & 1023;
                    float vv;
                    if (mask[b * SLEN + s]) vv = acc[mi][ni][r] * 0.125f + bcol;
                    else vv = trow[(size_t)b * DMODEL + col];
                    Co[(size_t)row * N + col] = vv;
                }
            }
    }
}

// ---------------- W[b,h] = KhT_rows @ VhT_rows^T (64x64) via MFMA; + Svec ----------------
// KhT/VhT: [1024 d][8192 s] bf16. Output Wb: bf16 image in pt-LDS order
// (elem idx = half*2048 + e*32 + rot(g,e)*8 + j, dd = half*32+g*8+j, rot=(g+(e>>1))&3).
// Svec[b*1024 + d] = sum_s VhT[d, b*1024+s] (fp32).
// BK=128: tile 64 rows x 128 k = 16KB; rows are 256B = 16 granules, rotated by row.
__global__ __launch_bounds__(256) void wker(
    const bf16_t* __restrict__ KhT, const bf16_t* __restrict__ VhT,
    bf16_t* __restrict__ Wb, float* __restrict__ Svec) {
    __shared__ __align__(16) char Ka[2][16384];
    __shared__ __align__(16) char Va[2][16384];
    __shared__ float red[64 * 16];
    const int h = blockIdx.x, b = blockIdx.y;
    const int tid = threadIdx.x;
    const int lane = tid & 63, wave = tid >> 6;
    const int lr = lane & 15, g = lane >> 4;

    // staging: granule gq = c*256+tid; row = gq>>4, slot = gq&15 holds src granule (slot-row)&15
    int srcOfs[4], dstOfs[4];
#pragma unroll
    for (int c = 0; c < 4; ++c) {
        const int gq = c * 256 + tid;
        const int row = gq >> 4, slot = gq & 15;
        const int gl = (slot - row) & 15;
        srcOfs[c] = row * MROWS + gl * 8;    // row stride 8192 elems
        dstOfs[c] = gq * 16;
    }
    const bf16_t* Kg = KhT + (size_t)(h * HD) * MROWS + b * SLEN;
    const bf16_t* Vg = VhT + (size_t)(h * HD) * MROWS + b * SLEN;

    f32x4 acc[4] = {};
    float svp[4] = {};

    // prologue: stage tile 0
#pragma unroll
    for (int c = 0; c < 4; ++c) gload_lds16(Kg + srcOfs[c], Ka[0] + dstOfs[c]);
#pragma unroll
    for (int c = 0; c < 4; ++c) gload_lds16(Vg + srcOfs[c], Va[0] + dstOfs[c]);

    for (int kt = 0; kt < 8; ++kt) {
        const int cur = kt & 1;
        if (kt < 7) {
            const int ko = (kt + 1) * 128;
#pragma unroll
            for (int c = 0; c < 4; ++c) gload_lds16(Kg + ko + srcOfs[c], Ka[cur ^ 1] + dstOfs[c]);
#pragma unroll
            for (int c = 0; c < 4; ++c) gload_lds16(Vg + ko + srcOfs[c], Va[cur ^ 1] + dstOfs[c]);
        }
        __syncthreads();  // drains vmcnt -> tile kt ready
        // fragment reads: row r, k-frag k4: byte = r*256 + ((k4*4 + g + r)&15)*16
        bf16x8 afr, bfr;
        __builtin_amdgcn_s_setprio(1);
#pragma unroll
        for (int k4 = 0; k4 < 4; ++k4) {
            const int ra = wave * 16 + lr;
            afr = *reinterpret_cast<const bf16x8*>(Ka[cur] + ra * 256 + (((k4 * 4 + g + ra) & 15) << 4));
#pragma unroll
            for (int ni = 0; ni < 4; ++ni) {
                const int rb = ni * 16 + lr;
                bfr = *reinterpret_cast<const bf16x8*>(Va[cur] + rb * 256 + (((k4 * 4 + g + rb) & 15) << 4));
                acc[ni] = __builtin_amdgcn_mfma_f32_16x16x32_bf16(afr, bfr, acc[ni], 0, 0, 0);
            }
        }
        __builtin_amdgcn_s_setprio(0);
        // Svec partials: sum own staged Va granules (row-local despite rotation)
#pragma unroll
        for (int c = 0; c < 4; ++c) {
            const bf16x8 vv = *reinterpret_cast<const bf16x8*>(Va[cur] + dstOfs[c]);
#pragma unroll
            for (int j = 0; j < 8; ++j) svp[c] += (float)vv[j];
        }
        __syncthreads();  // all reads done before next overwrite
    }

    // reduce Svec: thread's granule c sits at row c*16 + (tid>>4), seg tid&15
#pragma unroll
    for (int c = 0; c < 4; ++c) red[(c * 16 + (tid >> 4)) * 16 + (tid & 15)] = svp[c];
    __syncthreads();
    if (tid < 64) {
        float s = 0.f;
#pragma unroll
        for (int i = 0; i < 16; ++i) s += red[tid * 16 + i];
        Svec[(size_t)b * DMODEL + h * HD + tid] = s;
    }

    // write W image: C-frag elem (ni, r): e = wave*16 + g*4 + r, dd = ni*16 + lr
    bf16_t* Wo = Wb + ((size_t)(b * NH + h)) * 4096;
#pragma unroll
    for (int ni = 0; ni < 4; ++ni)
#pragma unroll
        for (int r = 0; r < 4; ++r) {
            const int e = wave * 16 + g * 4 + r;
            const int dd = ni * 16 + lr;
            const int half = dd >> 5, gg = (dd & 31) >> 3, j = dd & 7;
            const int idx = half * 2048 + e * 32 + (((gg + (e >> 1)) & 3) << 3) + j;
            Wo[idx] = (bf16_t)acc[ni][r];
        }
}

// ---------------- t[b,j] = -1e9 * (Svec[b,:] . wo[j,:]) + bo[j] (fp32 exact) ----------------
__global__ __launch_bounds__(256) void compute_t(
    const float* __restrict__ Svec, const float* __restrict__ wo,
    const float* __restrict__ bo, float* __restrict__ t) {
    __shared__ float Ss[DMODEL];
    const int b = blockIdx.x >> 8;
    const int j0 = (blockIdx.x & 255) * 4;
    const int tid = threadIdx.x;
#pragma unroll
    for (int i = 0; i < 4; ++i) {
        const int d = i * 256 + tid;
        Ss[d] = Svec[(size_t)b * DMODEL + d];
    }
    __syncthreads();
    const int wave = tid >> 6, lane = tid & 63;
    const int j = j0 + wave;
    f32x4 acc = {};
#pragma unroll
    for (int it = 0; it < 4; ++it) {
        const int idx = it * 256 + lane * 4;
        const f32x4 wv = *reinterpret_cast<const f32x4*>(&wo[(size_t)j * DMODEL + idx]);
        const f32x4 sv = *reinterpret_cast<const f32x4*>(&Ss[idx]);
        acc += wv * sv;
    }
    float tot = acc[0] + acc[1] + acc[2] + acc[3];
#pragma unroll
    for (int off = 1; off < 64; off <<= 1) tot += __shfl_xor(tot, off, 64);
    if (lane == 0) t[(size_t)b * DMODEL + j] = -1e9f * tot + bo[j];
}

// ---------------- PT[b, j, h*64+e] = sum_dd wo_b16[j, h*64+dd] * W[b,h][e,dd] ----------------
// MFMA: A = wo rows (j), B = W rows (e), contract dd (K=64). Block = (jt, h, b), 4 waves.
__global__ __launch_bounds__(256) void ptker(
    const bf16_t* __restrict__ wob, const bf16_t* __restrict__ Wb,
    bf16_t* __restrict__ PT) {
    __shared__ __align__(16) char Wimg[8192];           // 2 halves x 64 e x 32 cols
    __shared__ __align__(16) char Wo2[2][2][4096];      // [dbuf][half][64 j x 32 cols]
    const int jt = blockIdx.x, h = blockIdx.y, b = blockIdx.z;
    const int tid = threadIdx.x;
    const int lane = tid & 63, wave = tid >> 6;
    const int lr = lane & 15, g = lane >> 4;

    // stage W image (identity copy, pre-rotated by wker)
    const bf16_t* Wsrc = Wb + ((size_t)(b * NH + h)) * 4096;
    gload_lds16(Wsrc + tid * 8, Wimg + tid * 16);
    gload_lds16(Wsrc + 2048 + tid * 8, Wimg + 4096 + tid * 16);

    // wo tile staging: 64 rows x 64 cols as two 64B halves, granule rotation
    const int q = tid;                     // 256 granules per half
    const int row = q >> 2, slot = q & 3;
    const int gl = (slot - (row >> 1)) & 3;
    const int jbase = jt * 512;
    const bf16_t* wg = wob + (size_t)(jbase + row) * DMODEL + h * HD + gl * 8;
    // prologue: first wo tile
    gload_lds16(wg,      Wo2[0][0] + q * 16);
    gload_lds16(wg + 32, Wo2[0][1] + q * 16);
    __syncthreads();

    // hoist W fragments: bfr[kh][ni], row e = ni*16+lr
    bf16x8 bfr[2][4];
#pragma unroll
    for (int kh = 0; kh < 2; ++kh)
#pragma unroll
        for (int ni = 0; ni < 4; ++ni) {
            const int e = ni * 16 + lr;
            bfr[kh][ni] = *reinterpret_cast<const bf16x8*>(
                Wimg + kh * 4096 + e * 64 + (((g + (e >> 1)) & 3) << 4));
        }

    for (int it = 0; it < 8; ++it) {
        const int cur = it & 1;
        if (it < 7) {
            const bf16_t* wn = wg + (size_t)(it + 1) * 64 * DMODEL;
            gload_lds16(wn,      Wo2[cur ^ 1][0] + q * 16);
            gload_lds16(wn + 32, Wo2[cur ^ 1][1] + q * 16);
        }
        const int ra = wave * 16 + lr;
        const int ao = ra * 64 + (((g + (ra >> 1)) & 3) << 4);
        f32x4 acc[4] = {};
        bf16x8 afr;
        __builtin_amdgcn_s_setprio(1);
#pragma unroll
        for (int kh = 0; kh < 2; ++kh) {
            afr = *reinterpret_cast<const bf16x8*>(Wo2[cur][kh] + ao);
#pragma unroll
            for (int ni = 0; ni < 4; ++ni)
                acc[ni] = __builtin_amdgcn_mfma_f32_16x16x32_bf16(afr, bfr[kh][ni], acc[ni], 0, 0, 0);
        }
        __builtin_amdgcn_s_setprio(0);
        // store: row j = jbase + it*64 + wave*16 + g*4 + r; col = h*64 + ni*16 + lr
        bf16_t* Po = PT + (size_t)b * SLEN * DMODEL;
#pragma unroll
        for (int ni = 0; ni < 4; ++ni)
#pragma unroll
            for (int r = 0; r < 4; ++r) {
                const int j = jbase + it * 64 + wave * 16 + g * 4 + r;
                Po[(size_t)j * DMODEL + h * HD + ni * 16 + lr] = (bf16_t)acc[ni][r];
            }
        __syncthreads();
    }
}

extern "C" void kernel_launch(void* const* d_in, const int* in_sizes, int n_in,
                              void* d_out, int out_size, void* d_ws, size_t ws_size,
                              hipStream_t stream) {
    const float* q  = (const float*)d_in[0];
    const float* k  = (const float*)d_in[1];
    const float* v  = (const float*)d_in[2];
    const int* mask = (const int*)d_in[3];
    const float* wq = (const float*)d_in[4];
    const float* bq = (const float*)d_in[5];
    const float* wk = (const float*)d_in[6];
    const float* bk = (const float*)d_in[7];
    const float* wv = (const float*)d_in[8];
    const float* bv = (const float*)d_in[9];
    const float* wo = (const float*)d_in[10];
    const float* bo = (const float*)d_in[11];

    char* ws = (char*)d_ws;
    const size_t SZ_ACT = (size_t)MROWS * DMODEL * 2;  // 16 MB
    const size_t SZ_W = (size_t)DMODEL * DMODEL * 2;   // 2 MB
    const size_t SZ_WB = (size_t)0x100000;             // 1 MB (128 * 4096 * 2B)
    bf16_t* qb  = (bf16_t*)(ws);                 // later PT
    bf16_t* kb  = (bf16_t*)(ws + SZ_ACT);
    bf16_t* vb  = (bf16_t*)(ws + 2 * SZ_ACT);
    bf16_t* Qh  = (bf16_t*)(ws + 3 * SZ_ACT);
    bf16_t* KhT = (bf16_t*)(ws + 4 * SZ_ACT);
    bf16_t* VhT = (bf16_t*)(ws + 5 * SZ_ACT);
    char* tail = ws + 6 * SZ_ACT;
    bf16_t* wqb = (bf16_t*)(tail);
    bf16_t* wkb = (bf16_t*)(tail + SZ_W);
    bf16_t* wvb = (bf16_t*)(tail + 2 * SZ_W);
    bf16_t* wob = (bf16_t*)(tail + 3 * SZ_W);
    bf16_t* Wb  = (bf16_t*)(tail + 4 * SZ_W);
    float* Svec = (float*)(tail + 4 * SZ_W + SZ_WB);
    float* trow = (float*)(tail + 4 * SZ_W + SZ_WB + (size_t)(BATCH * DMODEL * 4));
    bf16_t* PT  = qb;

    const int n4a = MROWS * DMODEL / 4;
    const int n4w = DMODEL * DMODEL / 4;
    cvt7<<<dim3(n4a / 256, 7), 256, 0, stream>>>(q, k, v, wq, wk, wv, wo,
                                                 qb, kb, vb, wqb, wkb, wvb, wob, n4a, n4w);

    // projections: slice0 Q normal (8192x1024); slice1/2 K,V transposed (1024x8192)
    Slice sq{qb,  wqb, Qh,  bq, MROWS,  DMODEL, 0};
    Slice sk{wkb, kb,  KhT, bk, DMODEL, MROWS,  1};
    Slice sv{wvb, vb,  VhT, bv, DMODEL, MROWS,  1};
    gemm_tiled<0><<<dim3(768), 512, 0, stream>>>(sq, sk, sv, nullptr, nullptr);

    wker<<<dim3(NH, BATCH), 256, 0, stream>>>(KhT, VhT, Wb, Svec);
    compute_t<<<dim3(2048), 256, 0, stream>>>(Svec, wo, bo, trow);
    ptker<<<dim3(2, NH, BATCH), 256, 0, stream>>>(wob, Wb, PT);

    Slice so{Qh, PT, d_out, bo, MROWS, DMODEL, 0};
    gemm_tiled<1><<<dim3(256), 512, 0, stream>>>(so, so, so, trow, mask);
}